// Round 1
// 270.780 us; speedup vs baseline: 1.0569x; 1.0569x over previous
//
#include <hip/hip_runtime.h>
#include <math.h>

// NeuralMemory on MI355X — R9: rgemm_k rewrite.
// R8's rgemm had 16-way bank conflicts on every transpose ds_write_b32
// (SQ_LDS_BANK_CONFLICT == write count) + no prefetch + 8 waves/CU.
// R9: conflict-free XOR-swizzled [col][token-pair] LDS layout (stride 64
// shorts; slot = q ^ (s2(c)<<2) ^ (s4(c)<<4), 32 banks x 2 lanes on writes,
// aligned-b128 swizzled reads), software prefetch of next K-chunk across the
// barrier, 512-thread blocks (8 waves, wave tile 64x32) for 16 waves/CU.

#define NTOK 32768
#define NM ((size_t)NTOK * 256)
#define LRc 1e-3f
#define WDc 1e-2f
#define EPSc 1e-8f

typedef __attribute__((ext_vector_type(8))) short bf16x8;
typedef __attribute__((ext_vector_type(4))) float f32x4;

__device__ __forceinline__ float b2f(unsigned short u) {
    union { unsigned int i; float f; } c;
    c.i = ((unsigned int)u) << 16;
    return c.f;
}
__device__ __forceinline__ unsigned short f2b(float f) {
    union { float f; unsigned int i; } c;
    c.f = f;
    unsigned int i = c.i;
    return (unsigned short)((i + 0x7FFFu + ((i >> 16) & 1u)) >> 16);
}
__device__ __forceinline__ float sigm(float z) { return 1.f / (1.f + __expf(-z)); }
__device__ __forceinline__ float siluf(float z) { return z * sigm(z); }
__device__ __forceinline__ float dsiluf(float z) {
    float s = sigm(z);
    return s * (1.f + z * (1.f - s));
}
__device__ __forceinline__ void unpack4(uint2 u, float* f) {
    f[0] = b2f(u.x & 0xFFFF); f[1] = b2f(u.x >> 16);
    f[2] = b2f(u.y & 0xFFFF); f[3] = b2f(u.y >> 16);
}
__device__ __forceinline__ uint2 pack4(const float* f) {
    uint2 o;
    o.x = (unsigned)f2b(f[0]) | ((unsigned)f2b(f[1]) << 16);
    o.y = (unsigned)f2b(f[2]) | ((unsigned)f2b(f[3]) << 16);
    return o;
}

#define WSTR 264   // W tile row stride in shorts (33x 16B units, odd => rotate)
#define SSTR 40    // scratch row stride in shorts (80 B, 16B-aligned)

// ---------------------------------------------------------------------------
// Operand-swapped tall GEMM: C[M,256] = X[M,256] @ B with Bt[n][k]=B[k][n].
// Grid (2 n-halves, M/128 [, z]); block 512 thr = 8 waves; wave = 16 tokens
// x 128 ncols (8 MFMA col-tiles). W half-tile in LDS.
// EPI 0: Cb = X@B (batched z)                         projections
// EPI 1: z=acc+bias; Zout=z; Cb = X+silu(z)           fwd layer 0
// EPI 5: z=acc+bias; h2=X+silu(z); dh=alr'* (h2-V);   fwd layer 1 + bwd elem
//        dz=dh*dsilu(z); Cb=dz; Rout=dh
// EPI 2: dz0=(acc+Rin)*dsilu(Zin); Cb=dz0             bwd layer 0
// EPI 3: Cb = X + silu(acc+bias)                      retrieved L0
// EPI 4: Cf = X + silu(acc+bias)  (fp32 out)          retrieved L1
// ---------------------------------------------------------------------------
template <int EPI>
__global__ __launch_bounds__(512, 4) void wgemm_k(
    const unsigned short* __restrict__ A, const unsigned short* __restrict__ Bt,
    const float* __restrict__ bias, const unsigned short* __restrict__ Rin,
    const unsigned short* __restrict__ Zin, const unsigned short* __restrict__ Vb,
    const float* __restrict__ alr, unsigned short* __restrict__ Cb,
    float* __restrict__ Cf, unsigned short* __restrict__ Zout,
    unsigned short* __restrict__ Rout, size_t zcs) {
    __shared__ unsigned short Ws[128 * WSTR];
    __shared__ unsigned short Sc[8][16 * SSTR];
    Bt += (size_t)blockIdx.z * 65536;
    Cb += (size_t)blockIdx.z * zcs;
    const int n0 = blockIdx.x * 128, m0 = blockIdx.y * 128;
    const int tid = threadIdx.x, lane = tid & 63, wv = tid >> 6;
    const int cc = lane & 15, q = lane >> 4;

    // ---- X-frag loads: 8 instrs off one base (imm offsets), 8 KB/wave in flight
    const int t0 = m0 + wv * 16;
    const unsigned short* xp = A + (size_t)(t0 + cc) * 256 + q * 8;
    bf16x8 xf[8];
#pragma unroll
    for (int c = 0; c < 8; c++) xf[c] = *(const bf16x8*)(xp + c * 32);

    // ---- W half-tile fill: [128 n-rows][256 k] shorts, padded stride
#pragma unroll
    for (int it = 0; it < 8; it++) {
        int i = it * 512 + tid;
        int row = i >> 5, g8 = i & 31;
        *(uint4*)&Ws[row * WSTR + g8 * 8] =
            *(const uint4*)(Bt + (size_t)(n0 + row) * 256 + g8 * 8);
    }
    __syncthreads();

    f32x4 acc[8];
#pragma unroll
    for (int t = 0; t < 8; t++) acc[t] = (f32x4){0.f, 0.f, 0.f, 0.f};

#pragma unroll
    for (int c = 0; c < 8; c++) {
#pragma unroll
        for (int nt = 0; nt < 8; nt++) {
            bf16x8 wf = *(const bf16x8*)&Ws[(nt * 16 + cc) * WSTR + c * 32 + q * 8];
            acc[nt] = __builtin_amdgcn_mfma_f32_16x16x32_bf16(wf, xf[c],
                                                              acc[nt], 0, 0, 0);
        }
    }

    // ---- epilogue: lane holds token t0+cc, cols nt*16 + 4q + r (r=0..3)
    const int tok = t0 + cc;
    float lalr = 0.f;
    if (EPI == 5) lalr = alr[tok] * (2.f / 256.f);
    unsigned short* sc = &Sc[wv][0];
    const int rtok = lane >> 2, roct = (lane & 3) * 8;  // repack read indices

#pragma unroll
    for (int pr = 0; pr < 4; pr++) {  // tile pairs (2pr, 2pr+1) = 32 cols
        float o2[2][4], z2[2][4];     // primary / secondary quad outputs
#pragma unroll
        for (int h = 0; h < 2; h++) {
            const int nt = pr * 2 + h;
            const int gcol = n0 + nt * 16 + q * 4;
            const size_t off = (size_t)tok * 256 + gcol;
            f32x4 c = acc[nt];
            float v[4] = {c[0], c[1], c[2], c[3]};
            if (EPI == 0) {
#pragma unroll
                for (int r = 0; r < 4; r++) o2[h][r] = v[r];
            } else if (EPI == 1) {
                float bv[4], a[4];
                *(float4*)bv = *(const float4*)(bias + gcol);
                unpack4(*(const uint2*)(A + off), a);
#pragma unroll
                for (int r = 0; r < 4; r++) {
                    float z = v[r] + bv[r];
                    z2[h][r] = z;
                    o2[h][r] = a[r] + siluf(z);
                }
            } else if (EPI == 5) {
                float bv[4], a[4], vv[4];
                *(float4*)bv = *(const float4*)(bias + gcol);
                unpack4(*(const uint2*)(A + off), a);
                unpack4(*(const uint2*)(Vb + off), vv);
#pragma unroll
                for (int r = 0; r < 4; r++) {
                    float z = v[r] + bv[r];
                    float h2 = a[r] + siluf(z);
                    float dh = lalr * (h2 - vv[r]);
                    o2[h][r] = dh * dsiluf(z);  // dz
                    z2[h][r] = dh;              // dh
                }
            } else if (EPI == 2) {
                float ri[4], zi[4];
                unpack4(*(const uint2*)(Rin + off), ri);
                unpack4(*(const uint2*)(Zin + off), zi);
#pragma unroll
                for (int r = 0; r < 4; r++)
                    o2[h][r] = (v[r] + ri[r]) * dsiluf(zi[r]);
            } else {  // EPI 3 / 4
                float bv[4], a[4];
                *(float4*)bv = *(const float4*)(bias + gcol);
                unpack4(*(const uint2*)(A + off), a);
#pragma unroll
                for (int r = 0; r < 4; r++) o2[h][r] = a[r] + siluf(v[r] + bv[r]);
            }
            if (EPI == 4) {  // fp32 direct store: 4 lanes x 16 B = 64 B segs
                *(float4*)(Cf + off) = *(float4*)o2[h];
            }
        }
        if (EPI == 4) continue;
        // repack via wave-private scratch -> 64 B segment stores
#pragma unroll
        for (int h = 0; h < 2; h++)
            *(uint2*)&sc[cc * SSTR + h * 16 + q * 4] = pack4(o2[h]);
        uint4 pk = *(const uint4*)&sc[rtok * SSTR + roct];
        *(uint4*)(Cb + (size_t)(t0 + rtok) * 256 + n0 + pr * 32 + roct) = pk;
        if (EPI == 1 || EPI == 5) {  // second output (Zout / Rout)
#pragma unroll
            for (int h = 0; h < 2; h++)
                *(uint2*)&sc[cc * SSTR + h * 16 + q * 4] = pack4(z2[h]);
            uint4 pk2 = *(const uint4*)&sc[rtok * SSTR + roct];
            unsigned short* P2 = (EPI == 1) ? Zout : Rout;
            *(uint4*)(P2 + (size_t)(t0 + rtok) * 256 + n0 + pr * 32 + roct) = pk2;
        }
    }
}

// ---------------------------------------------------------------------------
// Reduction GEMM (weight grads): C[i][j] = sum_t A[t][i] B[t][j], split-K.
// R9: conflict-free swizzled transpose staging + prefetch + 8 waves/block.
// LDS layout per matrix: [128 cols][32 uint slots]; token-pair q of col c at
// slot q ^ (s2(c)<<2) ^ (s4(c)<<4), s2=((c>>3)^c)&3, s4=((c>>2)^(c>>5))&1.
// Writes: 32 banks x 2 lanes (free). Reads: b128 at block fkb^s2^(s4<<2),
// 16B-aligned, 8 distinct bank-groups per 8 lanes (free), tokens in order.
// ---------------------------------------------------------------------------
__global__ __launch_bounds__(512, 4) void rgemm_k(
    const unsigned short* __restrict__ Kb, const unsigned short* __restrict__ h1b,
    const unsigned short* __restrict__ dz0b,
    const unsigned short* __restrict__ dz1b, float* __restrict__ pbuf) {
    __shared__ unsigned short As[128 * 64];
    __shared__ unsigned short Bs2[128 * 64];
    const int z = blockIdx.z, layer = z >> 6, zc = z & 63;
    const unsigned short* Ag = layer ? h1b : Kb;
    const unsigned short* Bg = layer ? dz1b : dz0b;
    const int t0 = zc * 512;
    const int j0 = blockIdx.x * 128, i0 = blockIdx.y * 128;
    const int tid = threadIdx.x, lane = tid & 63, wave = tid >> 6;

    // staging role: threads 0-255 stage A, 256-511 stage B
    const int half = tid >> 8;
    const int t9 = tid & 255;
    const int ptq = t9 >> 4;          // token pair 0..15
    const int pi = (t9 & 15) * 8;     // col group base
    const unsigned short* sg = half ? Bg : Ag;
    const int nb = half ? j0 : i0;
    unsigned int* dst = (unsigned int*)(half ? Bs2 : As);
    const unsigned short* gp = sg + (size_t)(t0 + ptq * 2) * 256 + nb + pi;

    // wave output tile: 64 rows (i) x 32 cols (j)
    const int wr = (wave >> 2) * 64, wc = (wave & 3) * 32;
    const int fr = lane & 15, fkb = lane >> 4;

    f32x4 acc[4][2];
#pragma unroll
    for (int i = 0; i < 4; i++)
#pragma unroll
        for (int j = 0; j < 2; j++) acc[i][j] = (f32x4){0.f, 0.f, 0.f, 0.f};

    uint4 u0 = *(const uint4*)gp;
    uint4 u1 = *(const uint4*)(gp + 256);
    gp += 32 * 256;

    for (int it = 0; it < 16; it++) {
        // transpose-write: pack (token 2q, 2q+1) per col, swizzled slot
        const unsigned int* w0 = (const unsigned int*)&u0;
        const unsigned int* w1 = (const unsigned int*)&u1;
#pragma unroll
        for (int ii = 0; ii < 8; ii++) {
            unsigned int lo = (w0[ii >> 1] >> (16 * (ii & 1))) & 0xFFFFu;
            unsigned int hi = (w1[ii >> 1] >> (16 * (ii & 1))) & 0xFFFFu;
            const int col = pi + ii;
            const int s2 = ((col >> 3) ^ col) & 3;
            const int s4 = ((col >> 2) ^ (col >> 5)) & 1;
            dst[col * 32 + (ptq ^ (s2 << 2) ^ (s4 << 4))] = lo | (hi << 16);
        }
        __syncthreads();
        if (it < 15) {  // prefetch next K-chunk; latency hides under MFMA phase
            u0 = *(const uint4*)gp;
            u1 = *(const uint4*)(gp + 256);
            gp += 32 * 256;
        }
        bf16x8 af[4], bfr[2];
#pragma unroll
        for (int i = 0; i < 4; i++) {
            const int col = wr + i * 16 + fr;
            const int s2 = ((col >> 3) ^ col) & 3;
            const int s4 = ((col >> 2) ^ (col >> 5)) & 1;
            af[i] = *(const bf16x8*)&As[col * 64 + (fkb ^ s2 ^ (s4 << 2)) * 8];
        }
#pragma unroll
        for (int j = 0; j < 2; j++) {
            const int col = wc + j * 16 + fr;
            const int s2 = ((col >> 3) ^ col) & 3;
            const int s4 = ((col >> 2) ^ (col >> 5)) & 1;
            bfr[j] = *(const bf16x8*)&Bs2[col * 64 + (fkb ^ s2 ^ (s4 << 2)) * 8];
        }
#pragma unroll
        for (int i = 0; i < 4; i++)
#pragma unroll
            for (int j = 0; j < 2; j++)
                acc[i][j] = __builtin_amdgcn_mfma_f32_16x16x32_bf16(
                    af[i], bfr[j], acc[i][j], 0, 0, 0);
        __syncthreads();
    }

    float* P = pbuf + (size_t)((layer << 6) + zc) * 65536;
    const int r0 = fkb * 4;
#pragma unroll
    for (int mi = 0; mi < 4; mi++)
#pragma unroll
        for (int ni = 0; ni < 2; ni++) {
            f32x4 c = acc[mi][ni];
#pragma unroll
            for (int r = 0; r < 4; r++)
                P[(size_t)(i0 + wr + mi * 16 + r0 + r) * 256 +
                  (j0 + wc + ni * 16 + fr)] = c[r];
        }
}

__global__ void reduce_k(const float* __restrict__ pbuf, float* __restrict__ accW) {
    int idx = blockIdx.x * 256 + threadIdx.x;  // 131072
    int layer = idx >> 16, rc = idx & 65535;
    const float* p = pbuf + (size_t)layer * 64 * 65536 + rc;
    float s = 0.f;
#pragma unroll 8
    for (int c = 0; c < 64; c++) s += p[(size_t)c * 65536];
    accW[idx] = s;
}

// column sums of a bf16 [32768,256] matrix -> gb[256]
__global__ __launch_bounds__(256) void colsum_k(const unsigned short* __restrict__ dz,
                                                float* __restrict__ gb) {
    const int col = threadIdx.x;
    const size_t r0 = (size_t)blockIdx.x * 128;
    float s0 = 0, s1 = 0, s2 = 0, s3 = 0;
    for (int r = 0; r < 128; r += 4) {
        s0 += b2f(dz[(r0 + r) * 256 + col]);
        s1 += b2f(dz[(r0 + r + 1) * 256 + col]);
        s2 += b2f(dz[(r0 + r + 2) * 256 + col]);
        s3 += b2f(dz[(r0 + r + 3) * 256 + col]);
    }
    atomicAdd(&gb[col], s0 + s1 + s2 + s3);
}

// x fp32 -> xb bf16 + alr = 0.1*sigmoid(x@Wlr+blr), one wave per row
__global__ __launch_bounds__(256) void prep_k(const float* __restrict__ x,
                                              const float* __restrict__ Wlr,
                                              const float* __restrict__ blr,
                                              unsigned short* __restrict__ xb,
                                              float* __restrict__ alr) {
    const int wave = threadIdx.x >> 6, lane = threadIdx.x & 63;
    const int r = blockIdx.x * 4 + wave;
    float4 w = *(const float4*)(Wlr + lane * 4);
    float4 v = *(const float4*)(x + (size_t)r * 256 + lane * 4);
    float s = v.x * w.x + v.y * w.y + v.z * w.z + v.w * w.w;
    unsigned int p0 = (unsigned int)f2b(v.x) | ((unsigned int)f2b(v.y) << 16);
    unsigned int p1 = (unsigned int)f2b(v.z) | ((unsigned int)f2b(v.w) << 16);
    *(uint2*)(xb + (size_t)r * 256 + lane * 4) = make_uint2(p0, p1);
#pragma unroll
    for (int off = 32; off; off >>= 1) s += __shfl_down(s, off);
    if (lane == 0) alr[r] = 0.1f * sigm(s + blr[0]);
}

// weight prep: z=0..4 transpose+cvt {Wk,Wq,Wv,Ws0,Ws1}; z=5 straight cvt Ws1
__global__ void wprep_k(const float* __restrict__ Wk, const float* __restrict__ Wq,
                        const float* __restrict__ Wv, const float* __restrict__ Ws,
                        unsigned short* __restrict__ wt) {
    const int z = blockIdx.y;
    const int idx = blockIdx.x * 256 + threadIdx.x;  // 0..65535
    const float* src = z == 0 ? Wk : z == 1 ? Wq : z == 2 ? Wv
                     : z == 3 ? Ws : Ws + 65536;
    unsigned short* dst = wt + (size_t)z * 65536;
    float v = src[idx];
    if (z == 5)
        dst[idx] = f2b(v);
    else
        dst[(idx & 255) * 256 + (idx >> 8)] = f2b(v);
}

__global__ void adamw_w_k(const float* __restrict__ Ws,
                          const float* __restrict__ accW,
                          unsigned short* __restrict__ nWt,
                          float* __restrict__ outSW) {
    int idx = blockIdx.x * 256 + threadIdx.x;  // 131072
    float g = accW[idx];
    outSW[idx] = -g;
    float nw = Ws[idx] * (1.f - LRc * WDc) - LRc * g / (fabsf(g) + EPSc);
    int l = idx >> 16, k = (idx >> 8) & 255, n = idx & 255;
    nWt[(size_t)l * 65536 + n * 256 + k] = f2b(nw);
}

__global__ void adamw_b_k(const float* __restrict__ bs,
                          const float* __restrict__ accB,
                          float* __restrict__ nb, float* __restrict__ outSb) {
    int idx = blockIdx.x * 256 + threadIdx.x;  // 512
    float g = accB[idx];
    outSb[idx] = -g;
    nb[idx] = bs[idx] * (1.f - LRc * WDc) - LRc * g / (fabsf(g) + EPSc);
}

__global__ void zero_k(float* p, int n) {
    int i = blockIdx.x * 256 + threadIdx.x;
    if (i < n) p[i] = 0.f;
}

extern "C" void kernel_launch(void* const* d_in, const int* in_sizes, int n_in,
                              void* d_out, int out_size, void* d_ws,
                              size_t ws_size, hipStream_t stream) {
    const float* x = (const float*)d_in[0];
    const float* Wk = (const float*)d_in[1];
    const float* Wq = (const float*)d_in[2];
    const float* Wv = (const float*)d_in[3];
    const float* Wlr = (const float*)d_in[4];
    const float* blr = (const float*)d_in[5];
    const float* Ws = (const float*)d_in[6];
    const float* bs = (const float*)d_in[7];

    unsigned short* S = (unsigned short*)d_ws;
    unsigned short* xb = S + 0 * NM;  // dead after proj; reused as r1b
    unsigned short* Kb = S + 1 * NM;
    unsigned short* Qb = S + 2 * NM;
    unsigned short* Vb = S + 3 * NM;
    unsigned short* z0b = S + 4 * NM;
    unsigned short* h1b = S + 5 * NM;
    unsigned short* dz1b = S + 6 * NM;
    unsigned short* dh2b = S + 7 * NM;
    unsigned short* dz0b = S + 8 * NM;
    float* pbuf = (float*)(S + 9 * NM);  // 32 MB (slots 9-10)
    unsigned short* r1b = xb;

    unsigned short* wt = S + 11 * NM;
    unsigned short* W0t = wt + 3 * 65536;
    unsigned short* W1t = wt + 4 * 65536;
    unsigned short* W1b = wt + 5 * 65536;
    unsigned short* nW0t = wt + 6 * 65536;
    unsigned short* nW1t = wt + 7 * 65536;
    float* ft = (float*)(wt + 8 * 65536);
    float* alr = ft;              // 32768
    float* accW = ft + 32768;     // 131072
    float* accB = accW + 131072;  // 512
    float* nb = accB + 512;       // 512

    float* out_ret = (float*)d_out;
    float* out_sW = out_ret + NM;
    float* out_sb = out_sW + 131072;

    dim3 blk5(512);
    dim3 blk(256);
    dim3 g_tall(2, 256);

    zero_k<<<2, blk, 0, stream>>>(accB, 512);
    prep_k<<<8192, blk, 0, stream>>>(x, Wlr, blr, xb, alr);
    wprep_k<<<dim3(256, 6), blk, 0, stream>>>(Wk, Wq, Wv, Ws, wt);

    // projections K,Q,V (batched over z)
    wgemm_k<0><<<dim3(2, 256, 3), blk5, 0, stream>>>(
        xb, wt, nullptr, nullptr, nullptr, nullptr, nullptr, Kb, nullptr,
        nullptr, nullptr, NM);

    // fwd layer 0: h1 = K + silu(K@W0 + b0); saves z0
    wgemm_k<1><<<g_tall, blk5, 0, stream>>>(Kb, W0t, bs, nullptr, nullptr,
                                            nullptr, nullptr, h1b, nullptr,
                                            z0b, nullptr, 0);

    // fwd layer 1 + bwd elementwise: dz1, dh2
    wgemm_k<5><<<g_tall, blk5, 0, stream>>>(h1b, W1t, bs + 256, nullptr,
                                            nullptr, Vb, alr, dz1b, nullptr,
                                            nullptr, dh2b, 0);
    colsum_k<<<256, blk, 0, stream>>>(dz1b, accB + 256);

    // bwd layer 0: dz0 = (dz1@W1^T + dh2) * dsilu(z0)
    wgemm_k<2><<<g_tall, blk5, 0, stream>>>(dz1b, W1b, nullptr, dh2b, z0b,
                                            nullptr, nullptr, dz0b, nullptr,
                                            nullptr, nullptr, 0);
    colsum_k<<<256, blk, 0, stream>>>(dz0b, accB);

    // weight grads: swizzled transpose-on-load split-K partials + reduce
    rgemm_k<<<dim3(2, 2, 128), blk5, 0, stream>>>(Kb, h1b, dz0b, dz1b, pbuf);
    reduce_k<<<512, blk, 0, stream>>>(pbuf, accW);

    // AdamW + surprises
    adamw_w_k<<<512, blk, 0, stream>>>(Ws, accW, nW0t, out_sW);
    adamw_b_k<<<2, blk, 0, stream>>>(bs, accB, nb, out_sb);

    // retrieved with new weights (two tall passes)
    wgemm_k<3><<<g_tall, blk5, 0, stream>>>(Qb, nW0t, nb, nullptr, nullptr,
                                            nullptr, nullptr, r1b, nullptr,
                                            nullptr, nullptr, 0);
    wgemm_k<4><<<g_tall, blk5, 0, stream>>>(r1b, nW1t, nb + 256, nullptr,
                                            nullptr, nullptr, nullptr, nullptr,
                                            out_ret, nullptr, nullptr, 0);
}

// Round 2
// 252.430 us; speedup vs baseline: 1.1338x; 1.0727x over previous
//
#include <hip/hip_runtime.h>
#include <math.h>

// NeuralMemory on MI355X — R10: fusion + split-K reduction.
// R9 fixed rgemm bank conflicts (286->271 us). R10 cuts intermediate traffic
// and dispatch count: rgemm split-K 64->32 (pbuf 33.5->16.8 MB, halves the
// HBM-verified pbuf write + reduce read), prep/wprep/zero fused to one
// launch, both colsums fused to one launch, reduce+adamw_w+adamw_b fused to
// one gradstep kernel (accW buffer deleted). 15 -> 10 dispatches.

#define NTOK 32768
#define NM ((size_t)NTOK * 256)
#define LRc 1e-3f
#define WDc 1e-2f
#define EPSc 1e-8f

typedef __attribute__((ext_vector_type(8))) short bf16x8;
typedef __attribute__((ext_vector_type(4))) float f32x4;

__device__ __forceinline__ float b2f(unsigned short u) {
    union { unsigned int i; float f; } c;
    c.i = ((unsigned int)u) << 16;
    return c.f;
}
__device__ __forceinline__ unsigned short f2b(float f) {
    union { float f; unsigned int i; } c;
    c.f = f;
    unsigned int i = c.i;
    return (unsigned short)((i + 0x7FFFu + ((i >> 16) & 1u)) >> 16);
}
__device__ __forceinline__ float sigm(float z) { return 1.f / (1.f + __expf(-z)); }
__device__ __forceinline__ float siluf(float z) { return z * sigm(z); }
__device__ __forceinline__ float dsiluf(float z) {
    float s = sigm(z);
    return s * (1.f + z * (1.f - s));
}
__device__ __forceinline__ void unpack4(uint2 u, float* f) {
    f[0] = b2f(u.x & 0xFFFF); f[1] = b2f(u.x >> 16);
    f[2] = b2f(u.y & 0xFFFF); f[3] = b2f(u.y >> 16);
}
__device__ __forceinline__ uint2 pack4(const float* f) {
    uint2 o;
    o.x = (unsigned)f2b(f[0]) | ((unsigned)f2b(f[1]) << 16);
    o.y = (unsigned)f2b(f[2]) | ((unsigned)f2b(f[3]) << 16);
    return o;
}

#define WSTR 264   // W tile row stride in shorts (33x 16B units, odd => rotate)
#define SSTR 40    // scratch row stride in shorts (80 B, 16B-aligned)

// ---------------------------------------------------------------------------
// Operand-swapped tall GEMM: C[M,256] = X[M,256] @ B with Bt[n][k]=B[k][n].
// Grid (2 n-halves, M/128 [, z]); block 512 thr = 8 waves; wave = 16 tokens
// x 128 ncols (8 MFMA col-tiles). W half-tile in LDS.
// EPI 0: Cb = X@B (batched z)                         projections
// EPI 1: z=acc+bias; Zout=z; Cb = X+silu(z)           fwd layer 0
// EPI 5: z=acc+bias; h2=X+silu(z); dh=alr'* (h2-V);   fwd layer 1 + bwd elem
//        dz=dh*dsilu(z); Cb=dz; Rout=dh
// EPI 2: dz0=(acc+Rin)*dsilu(Zin); Cb=dz0             bwd layer 0
// EPI 3: Cb = X + silu(acc+bias)                      retrieved L0
// EPI 4: Cf = X + silu(acc+bias)  (fp32 out)          retrieved L1
// ---------------------------------------------------------------------------
template <int EPI>
__global__ __launch_bounds__(512, 4) void wgemm_k(
    const unsigned short* __restrict__ A, const unsigned short* __restrict__ Bt,
    const float* __restrict__ bias, const unsigned short* __restrict__ Rin,
    const unsigned short* __restrict__ Zin, const unsigned short* __restrict__ Vb,
    const float* __restrict__ alr, unsigned short* __restrict__ Cb,
    float* __restrict__ Cf, unsigned short* __restrict__ Zout,
    unsigned short* __restrict__ Rout, size_t zcs) {
    __shared__ unsigned short Ws[128 * WSTR];
    __shared__ unsigned short Sc[8][16 * SSTR];
    Bt += (size_t)blockIdx.z * 65536;
    Cb += (size_t)blockIdx.z * zcs;
    const int n0 = blockIdx.x * 128, m0 = blockIdx.y * 128;
    const int tid = threadIdx.x, lane = tid & 63, wv = tid >> 6;
    const int cc = lane & 15, q = lane >> 4;

    // ---- X-frag loads: 8 instrs off one base (imm offsets), 8 KB/wave in flight
    const int t0 = m0 + wv * 16;
    const unsigned short* xp = A + (size_t)(t0 + cc) * 256 + q * 8;
    bf16x8 xf[8];
#pragma unroll
    for (int c = 0; c < 8; c++) xf[c] = *(const bf16x8*)(xp + c * 32);

    // ---- W half-tile fill: [128 n-rows][256 k] shorts, padded stride
#pragma unroll
    for (int it = 0; it < 8; it++) {
        int i = it * 512 + tid;
        int row = i >> 5, g8 = i & 31;
        *(uint4*)&Ws[row * WSTR + g8 * 8] =
            *(const uint4*)(Bt + (size_t)(n0 + row) * 256 + g8 * 8);
    }
    __syncthreads();

    f32x4 acc[8];
#pragma unroll
    for (int t = 0; t < 8; t++) acc[t] = (f32x4){0.f, 0.f, 0.f, 0.f};

#pragma unroll
    for (int c = 0; c < 8; c++) {
#pragma unroll
        for (int nt = 0; nt < 8; nt++) {
            bf16x8 wf = *(const bf16x8*)&Ws[(nt * 16 + cc) * WSTR + c * 32 + q * 8];
            acc[nt] = __builtin_amdgcn_mfma_f32_16x16x32_bf16(wf, xf[c],
                                                              acc[nt], 0, 0, 0);
        }
    }

    // ---- epilogue: lane holds token t0+cc, cols nt*16 + 4q + r (r=0..3)
    const int tok = t0 + cc;
    float lalr = 0.f;
    if (EPI == 5) lalr = alr[tok] * (2.f / 256.f);
    unsigned short* sc = &Sc[wv][0];
    const int rtok = lane >> 2, roct = (lane & 3) * 8;  // repack read indices

#pragma unroll
    for (int pr = 0; pr < 4; pr++) {  // tile pairs (2pr, 2pr+1) = 32 cols
        float o2[2][4], z2[2][4];     // primary / secondary quad outputs
#pragma unroll
        for (int h = 0; h < 2; h++) {
            const int nt = pr * 2 + h;
            const int gcol = n0 + nt * 16 + q * 4;
            const size_t off = (size_t)tok * 256 + gcol;
            f32x4 c = acc[nt];
            float v[4] = {c[0], c[1], c[2], c[3]};
            if (EPI == 0) {
#pragma unroll
                for (int r = 0; r < 4; r++) o2[h][r] = v[r];
            } else if (EPI == 1) {
                float bv[4], a[4];
                *(float4*)bv = *(const float4*)(bias + gcol);
                unpack4(*(const uint2*)(A + off), a);
#pragma unroll
                for (int r = 0; r < 4; r++) {
                    float z = v[r] + bv[r];
                    z2[h][r] = z;
                    o2[h][r] = a[r] + siluf(z);
                }
            } else if (EPI == 5) {
                float bv[4], a[4], vv[4];
                *(float4*)bv = *(const float4*)(bias + gcol);
                unpack4(*(const uint2*)(A + off), a);
                unpack4(*(const uint2*)(Vb + off), vv);
#pragma unroll
                for (int r = 0; r < 4; r++) {
                    float z = v[r] + bv[r];
                    float h2 = a[r] + siluf(z);
                    float dh = lalr * (h2 - vv[r]);
                    o2[h][r] = dh * dsiluf(z);  // dz
                    z2[h][r] = dh;              // dh
                }
            } else if (EPI == 2) {
                float ri[4], zi[4];
                unpack4(*(const uint2*)(Rin + off), ri);
                unpack4(*(const uint2*)(Zin + off), zi);
#pragma unroll
                for (int r = 0; r < 4; r++)
                    o2[h][r] = (v[r] + ri[r]) * dsiluf(zi[r]);
            } else {  // EPI 3 / 4
                float bv[4], a[4];
                *(float4*)bv = *(const float4*)(bias + gcol);
                unpack4(*(const uint2*)(A + off), a);
#pragma unroll
                for (int r = 0; r < 4; r++) o2[h][r] = a[r] + siluf(v[r] + bv[r]);
            }
            if (EPI == 4) {  // fp32 direct store: 4 lanes x 16 B = 64 B segs
                *(float4*)(Cf + off) = *(float4*)o2[h];
            }
        }
        if (EPI == 4) continue;
        // repack via wave-private scratch -> 64 B segment stores
#pragma unroll
        for (int h = 0; h < 2; h++)
            *(uint2*)&sc[cc * SSTR + h * 16 + q * 4] = pack4(o2[h]);
        uint4 pk = *(const uint4*)&sc[rtok * SSTR + roct];
        *(uint4*)(Cb + (size_t)(t0 + rtok) * 256 + n0 + pr * 32 + roct) = pk;
        if (EPI == 1 || EPI == 5) {  // second output (Zout / Rout)
#pragma unroll
            for (int h = 0; h < 2; h++)
                *(uint2*)&sc[cc * SSTR + h * 16 + q * 4] = pack4(z2[h]);
            uint4 pk2 = *(const uint4*)&sc[rtok * SSTR + roct];
            unsigned short* P2 = (EPI == 1) ? Zout : Rout;
            *(uint4*)(P2 + (size_t)(t0 + rtok) * 256 + n0 + pr * 32 + roct) = pk2;
        }
    }
}

// ---------------------------------------------------------------------------
// Reduction GEMM (weight grads): C[i][j] = sum_t A[t][i] B[t][j], split-K 32.
// Conflict-free swizzled transpose staging + prefetch + 8 waves/block (R9).
// LDS layout per matrix: [128 cols][32 uint slots]; token-pair q of col c at
// slot q ^ (s2(c)<<2) ^ (s4(c)<<4), s2=((c>>3)^c)&3, s4=((c>>2)^(c>>5))&1.
// Writes: 32 banks x 2 lanes (free). Reads: b128 at block fkb^s2^(s4<<2).
// R10: z = 64 (2 layers x 32 chunks of 1024 tokens) -> pbuf halved.
// ---------------------------------------------------------------------------
__global__ __launch_bounds__(512, 4) void rgemm_k(
    const unsigned short* __restrict__ Kb, const unsigned short* __restrict__ h1b,
    const unsigned short* __restrict__ dz0b,
    const unsigned short* __restrict__ dz1b, float* __restrict__ pbuf) {
    __shared__ unsigned short As[128 * 64];
    __shared__ unsigned short Bs2[128 * 64];
    const int z = blockIdx.z, layer = z >> 5, zc = z & 31;
    const unsigned short* Ag = layer ? h1b : Kb;
    const unsigned short* Bg = layer ? dz1b : dz0b;
    const int t0 = zc * 1024;
    const int j0 = blockIdx.x * 128, i0 = blockIdx.y * 128;
    const int tid = threadIdx.x, lane = tid & 63, wave = tid >> 6;

    // staging role: threads 0-255 stage A, 256-511 stage B
    const int half = tid >> 8;
    const int t9 = tid & 255;
    const int ptq = t9 >> 4;          // token pair 0..15
    const int pi = (t9 & 15) * 8;     // col group base
    const unsigned short* sg = half ? Bg : Ag;
    const int nb = half ? j0 : i0;
    unsigned int* dst = (unsigned int*)(half ? Bs2 : As);
    const unsigned short* gp = sg + (size_t)(t0 + ptq * 2) * 256 + nb + pi;

    // wave output tile: 64 rows (i) x 32 cols (j)
    const int wr = (wave >> 2) * 64, wc = (wave & 3) * 32;
    const int fr = lane & 15, fkb = lane >> 4;

    f32x4 acc[4][2];
#pragma unroll
    for (int i = 0; i < 4; i++)
#pragma unroll
        for (int j = 0; j < 2; j++) acc[i][j] = (f32x4){0.f, 0.f, 0.f, 0.f};

    uint4 u0 = *(const uint4*)gp;
    uint4 u1 = *(const uint4*)(gp + 256);
    gp += 32 * 256;

    for (int it = 0; it < 32; it++) {
        // transpose-write: pack (token 2q, 2q+1) per col, swizzled slot
        const unsigned int* w0 = (const unsigned int*)&u0;
        const unsigned int* w1 = (const unsigned int*)&u1;
#pragma unroll
        for (int ii = 0; ii < 8; ii++) {
            unsigned int lo = (w0[ii >> 1] >> (16 * (ii & 1))) & 0xFFFFu;
            unsigned int hi = (w1[ii >> 1] >> (16 * (ii & 1))) & 0xFFFFu;
            const int col = pi + ii;
            const int s2 = ((col >> 3) ^ col) & 3;
            const int s4 = ((col >> 2) ^ (col >> 5)) & 1;
            dst[col * 32 + (ptq ^ (s2 << 2) ^ (s4 << 4))] = lo | (hi << 16);
        }
        __syncthreads();
        if (it < 31) {  // prefetch next K-chunk; latency hides under MFMA phase
            u0 = *(const uint4*)gp;
            u1 = *(const uint4*)(gp + 256);
            gp += 32 * 256;
        }
        bf16x8 af[4], bfr[2];
#pragma unroll
        for (int i = 0; i < 4; i++) {
            const int col = wr + i * 16 + fr;
            const int s2 = ((col >> 3) ^ col) & 3;
            const int s4 = ((col >> 2) ^ (col >> 5)) & 1;
            af[i] = *(const bf16x8*)&As[col * 64 + (fkb ^ s2 ^ (s4 << 2)) * 8];
        }
#pragma unroll
        for (int j = 0; j < 2; j++) {
            const int col = wc + j * 16 + fr;
            const int s2 = ((col >> 3) ^ col) & 3;
            const int s4 = ((col >> 2) ^ (col >> 5)) & 1;
            bfr[j] = *(const bf16x8*)&Bs2[col * 64 + (fkb ^ s2 ^ (s4 << 2)) * 8];
        }
#pragma unroll
        for (int i = 0; i < 4; i++)
#pragma unroll
            for (int j = 0; j < 2; j++)
                acc[i][j] = __builtin_amdgcn_mfma_f32_16x16x32_bf16(
                    af[i], bfr[j], acc[i][j], 0, 0, 0);
        __syncthreads();
    }

    float* P = pbuf + (size_t)((layer << 5) + zc) * 65536;
    const int r0 = fkb * 4;
#pragma unroll
    for (int mi = 0; mi < 4; mi++)
#pragma unroll
        for (int ni = 0; ni < 2; ni++) {
            f32x4 c = acc[mi][ni];
#pragma unroll
            for (int r = 0; r < 4; r++)
                P[(size_t)(i0 + wr + mi * 16 + r0 + r) * 256 +
                  (j0 + wc + ni * 16 + fr)] = c[r];
        }
}

// ---------------------------------------------------------------------------
// gradstep: reduce pbuf (32 chunks) -> g; surprises; AdamW for W and b.
// blocks 0..511: weights (256 threads each). block 512: biases.
// ---------------------------------------------------------------------------
__global__ __launch_bounds__(256) void gradstep_k(
    const float* __restrict__ pbuf, const float* __restrict__ Ws,
    const float* __restrict__ bs, const float* __restrict__ accB,
    unsigned short* __restrict__ nWt, float* __restrict__ nb,
    float* __restrict__ outSW, float* __restrict__ outSb) {
    const int bi = blockIdx.x;
    if (bi < 512) {
        const int idx = bi * 256 + threadIdx.x;  // 0..131071
        const int layer = idx >> 16, rc = idx & 65535;
        const float* p = pbuf + (size_t)layer * 32 * 65536 + rc;
        float g = 0.f;
#pragma unroll 8
        for (int c = 0; c < 32; c++) g += p[(size_t)c * 65536];
        outSW[idx] = -g;
        float nw = Ws[idx] * (1.f - LRc * WDc) - LRc * g / (fabsf(g) + EPSc);
        const int l = idx >> 16, k = (idx >> 8) & 255, n = idx & 255;
        nWt[(size_t)l * 65536 + n * 256 + k] = f2b(nw);
    } else {
        for (int i = threadIdx.x; i < 512; i += 256) {
            float g = accB[i];
            outSb[i] = -g;
            nb[i] = bs[i] * (1.f - LRc * WDc) - LRc * g / (fabsf(g) + EPSc);
        }
    }
}

// column sums of two bf16 [32768,256] matrices -> gb[256..511] / gb[0..255]
__global__ __launch_bounds__(256) void colsum2_k(
    const unsigned short* __restrict__ dz1, const unsigned short* __restrict__ dz0,
    float* __restrict__ gb) {
    const int bi = blockIdx.x;
    const unsigned short* dz = (bi < 256) ? dz1 : dz0;
    float* g = (bi < 256) ? gb + 256 : gb;
    const int col = threadIdx.x;
    const size_t r0 = (size_t)(bi & 255) * 128;
    float s0 = 0, s1 = 0, s2 = 0, s3 = 0;
    for (int r = 0; r < 128; r += 4) {
        s0 += b2f(dz[(r0 + r) * 256 + col]);
        s1 += b2f(dz[(r0 + r + 1) * 256 + col]);
        s2 += b2f(dz[(r0 + r + 2) * 256 + col]);
        s3 += b2f(dz[(r0 + r + 3) * 256 + col]);
    }
    atomicAdd(&g[col], s0 + s1 + s2 + s3);
}

// ---------------------------------------------------------------------------
// prep_all: blocks 0..8191  -> x fp32 -> xb bf16 + alr (one wave per row)
//           blocks 8192..9727 -> weight transpose+cvt (z=0..4) / cvt (z=5)
//           block 9728      -> zero accB[512]
// ---------------------------------------------------------------------------
__global__ __launch_bounds__(256) void prep_all_k(
    const float* __restrict__ x, const float* __restrict__ Wlr,
    const float* __restrict__ blr, const float* __restrict__ Wk,
    const float* __restrict__ Wq, const float* __restrict__ Wv,
    const float* __restrict__ Ws, unsigned short* __restrict__ xb,
    float* __restrict__ alr, unsigned short* __restrict__ wt,
    float* __restrict__ accB) {
    const int bi = blockIdx.x;
    if (bi < 8192) {
        const int wave = threadIdx.x >> 6, lane = threadIdx.x & 63;
        const int r = bi * 4 + wave;
        float4 w = *(const float4*)(Wlr + lane * 4);
        float4 v = *(const float4*)(x + (size_t)r * 256 + lane * 4);
        float s = v.x * w.x + v.y * w.y + v.z * w.z + v.w * w.w;
        unsigned int p0 = (unsigned int)f2b(v.x) | ((unsigned int)f2b(v.y) << 16);
        unsigned int p1 = (unsigned int)f2b(v.z) | ((unsigned int)f2b(v.w) << 16);
        *(uint2*)(xb + (size_t)r * 256 + lane * 4) = make_uint2(p0, p1);
#pragma unroll
        for (int off = 32; off; off >>= 1) s += __shfl_down(s, off);
        if (lane == 0) alr[r] = 0.1f * sigm(s + blr[0]);
    } else if (bi < 9728) {
        const int b = bi - 8192;
        const int z = b >> 8;
        const int idx = (b & 255) * 256 + threadIdx.x;  // 0..65535
        const float* src = z == 0 ? Wk : z == 1 ? Wq : z == 2 ? Wv
                         : z == 3 ? Ws : Ws + 65536;
        unsigned short* dst = wt + (size_t)z * 65536;
        float v = src[idx];
        if (z == 5)
            dst[idx] = f2b(v);
        else
            dst[(idx & 255) * 256 + (idx >> 8)] = f2b(v);
    } else {
        accB[threadIdx.x] = 0.f;
        accB[threadIdx.x + 256] = 0.f;
    }
}

extern "C" void kernel_launch(void* const* d_in, const int* in_sizes, int n_in,
                              void* d_out, int out_size, void* d_ws,
                              size_t ws_size, hipStream_t stream) {
    const float* x = (const float*)d_in[0];
    const float* Wk = (const float*)d_in[1];
    const float* Wq = (const float*)d_in[2];
    const float* Wv = (const float*)d_in[3];
    const float* Wlr = (const float*)d_in[4];
    const float* blr = (const float*)d_in[5];
    const float* Ws = (const float*)d_in[6];
    const float* bs = (const float*)d_in[7];

    unsigned short* S = (unsigned short*)d_ws;
    unsigned short* xb = S + 0 * NM;  // dead after proj; reused as r1b
    unsigned short* Kb = S + 1 * NM;
    unsigned short* Qb = S + 2 * NM;
    unsigned short* Vb = S + 3 * NM;
    unsigned short* z0b = S + 4 * NM;
    unsigned short* h1b = S + 5 * NM;
    unsigned short* dz1b = S + 6 * NM;
    unsigned short* dh2b = S + 7 * NM;
    unsigned short* dz0b = S + 8 * NM;
    float* pbuf = (float*)(S + 9 * NM);  // 16 MB (slot 9): 2 layers x 32 chunks
    unsigned short* r1b = xb;

    unsigned short* wt = S + 11 * NM;
    unsigned short* W0t = wt + 3 * 65536;
    unsigned short* W1t = wt + 4 * 65536;
    unsigned short* W1b = wt + 5 * 65536;
    unsigned short* nW0t = wt + 6 * 65536;
    unsigned short* nW1t = wt + 7 * 65536;
    float* ft = (float*)(wt + 8 * 65536);
    float* alr = ft;              // 32768
    float* accB = ft + 32768;     // 512
    float* nb = accB + 512;       // 512

    float* out_ret = (float*)d_out;
    float* out_sW = out_ret + NM;
    float* out_sb = out_sW + 131072;

    dim3 blk5(512);
    dim3 blk(256);
    dim3 g_tall(2, 256);

    // prep: x->bf16 + alr, weight transpose/cvt, zero accB (one dispatch)
    prep_all_k<<<9729, blk, 0, stream>>>(x, Wlr, blr, Wk, Wq, Wv, Ws, xb, alr,
                                         wt, accB);

    // projections K,Q,V (batched over z)
    wgemm_k<0><<<dim3(2, 256, 3), blk5, 0, stream>>>(
        xb, wt, nullptr, nullptr, nullptr, nullptr, nullptr, Kb, nullptr,
        nullptr, nullptr, NM);

    // fwd layer 0: h1 = K + silu(K@W0 + b0); saves z0
    wgemm_k<1><<<g_tall, blk5, 0, stream>>>(Kb, W0t, bs, nullptr, nullptr,
                                            nullptr, nullptr, h1b, nullptr,
                                            z0b, nullptr, 0);

    // fwd layer 1 + bwd elementwise: dz1, dh2
    wgemm_k<5><<<g_tall, blk5, 0, stream>>>(h1b, W1t, bs + 256, nullptr,
                                            nullptr, Vb, alr, dz1b, nullptr,
                                            nullptr, dh2b, 0);

    // bwd layer 0: dz0 = (dz1@W1^T + dh2) * dsilu(z0)
    wgemm_k<2><<<g_tall, blk5, 0, stream>>>(dz1b, W1b, nullptr, dh2b, z0b,
                                            nullptr, nullptr, dz0b, nullptr,
                                            nullptr, nullptr, 0);

    // bias grads: both colsums in one dispatch
    colsum2_k<<<512, blk, 0, stream>>>(dz1b, dz0b, accB);

    // weight grads: swizzled transpose-on-load split-K partials
    rgemm_k<<<dim3(2, 2, 64), blk5, 0, stream>>>(Kb, h1b, dz0b, dz1b, pbuf);

    // reduce + surprises + AdamW (W and b) in one dispatch
    gradstep_k<<<513, blk, 0, stream>>>(pbuf, Ws, bs, accB, nW0t, nb, out_sW,
                                        out_sb);

    // retrieved with new weights (two tall passes)
    wgemm_k<3><<<g_tall, blk5, 0, stream>>>(Qb, nW0t, nb, nullptr, nullptr,
                                            nullptr, nullptr, r1b, nullptr,
                                            nullptr, nullptr, 0);
    wgemm_k<4><<<g_tall, blk5, 0, stream>>>(r1b, nW1t, nb + 256, nullptr,
                                            nullptr, nullptr, nullptr, nullptr,
                                            out_ret, nullptr, nullptr, 0);
}

// Round 3
// 247.321 us; speedup vs baseline: 1.1572x; 1.0207x over previous
//
#include <hip/hip_runtime.h>
#include <math.h>

// NeuralMemory on MI355X — R11: proj z-loop + colsum fusion.
// R10 = 252 us. R11: (1) projections become one (2,256)-grid kernel with an
// internal z-loop over {Wk,Wq,Wv} — X frags loaded ONCE per block (was 3x),
// W fills hit L2; (2) bias-grad colsums fused into EPI5/EPI2 epilogues via
// cc-group shfl_xor reduce + LDS accumulate + one global atomicAdd per col
// (deletes colsum2_k and its 32 MB re-read). 10 -> 9 dispatches.

#define NTOK 32768
#define NM ((size_t)NTOK * 256)
#define LRc 1e-3f
#define WDc 1e-2f
#define EPSc 1e-8f

typedef __attribute__((ext_vector_type(8))) short bf16x8;
typedef __attribute__((ext_vector_type(4))) float f32x4;

__device__ __forceinline__ float b2f(unsigned short u) {
    union { unsigned int i; float f; } c;
    c.i = ((unsigned int)u) << 16;
    return c.f;
}
__device__ __forceinline__ unsigned short f2b(float f) {
    union { float f; unsigned int i; } c;
    c.f = f;
    unsigned int i = c.i;
    return (unsigned short)((i + 0x7FFFu + ((i >> 16) & 1u)) >> 16);
}
__device__ __forceinline__ float sigm(float z) { return 1.f / (1.f + __expf(-z)); }
__device__ __forceinline__ float siluf(float z) { return z * sigm(z); }
__device__ __forceinline__ float dsiluf(float z) {
    float s = sigm(z);
    return s * (1.f + z * (1.f - s));
}
__device__ __forceinline__ void unpack4(uint2 u, float* f) {
    f[0] = b2f(u.x & 0xFFFF); f[1] = b2f(u.x >> 16);
    f[2] = b2f(u.y & 0xFFFF); f[3] = b2f(u.y >> 16);
}
__device__ __forceinline__ uint2 pack4(const float* f) {
    uint2 o;
    o.x = (unsigned)f2b(f[0]) | ((unsigned)f2b(f[1]) << 16);
    o.y = (unsigned)f2b(f[2]) | ((unsigned)f2b(f[3]) << 16);
    return o;
}

#define WSTR 264   // W tile row stride in shorts (33x 16B units, odd => rotate)
#define SSTR 40    // scratch row stride in shorts (80 B, 16B-aligned)

// ---------------------------------------------------------------------------
// Projections: K,Q,V = X @ {Wk,Wq,Wv} in one kernel, z-loop inside block.
// Grid (2 n-halves, 256 token-groups); block 512 = 8 waves; wave = 16 tokens.
// X frags loaded once; per z: fill W half-tile (L2-resident), MFMA, repack.
// ---------------------------------------------------------------------------
__global__ __launch_bounds__(512, 4) void wgemm3_k(
    const unsigned short* __restrict__ A, const unsigned short* __restrict__ wt,
    unsigned short* __restrict__ Kb, unsigned short* __restrict__ Qb,
    unsigned short* __restrict__ Vb) {
    __shared__ unsigned short Ws[128 * WSTR];
    __shared__ unsigned short Sc[8][16 * SSTR];
    const int n0 = blockIdx.x * 128, m0 = blockIdx.y * 128;
    const int tid = threadIdx.x, lane = tid & 63, wv = tid >> 6;
    const int cc = lane & 15, q = lane >> 4;
    const int t0 = m0 + wv * 16;

    const unsigned short* xp = A + (size_t)(t0 + cc) * 256 + q * 8;
    bf16x8 xf[8];
#pragma unroll
    for (int c = 0; c < 8; c++) xf[c] = *(const bf16x8*)(xp + c * 32);

    unsigned short* sc = &Sc[wv][0];
    const int rtok = lane >> 2, roct = (lane & 3) * 8;
    unsigned short* const outs[3] = {Kb, Qb, Vb};

    for (int z = 0; z < 3; z++) {
        __syncthreads();  // prior z's Ws reads complete before refill
#pragma unroll
        for (int it = 0; it < 8; it++) {
            int i = it * 512 + tid;
            int row = i >> 5, g8 = i & 31;
            *(uint4*)&Ws[row * WSTR + g8 * 8] =
                *(const uint4*)(wt + (size_t)z * 65536 +
                                (size_t)(n0 + row) * 256 + g8 * 8);
        }
        __syncthreads();

        f32x4 acc[8];
#pragma unroll
        for (int t = 0; t < 8; t++) acc[t] = (f32x4){0.f, 0.f, 0.f, 0.f};
#pragma unroll
        for (int c = 0; c < 8; c++) {
#pragma unroll
            for (int nt = 0; nt < 8; nt++) {
                bf16x8 wf =
                    *(const bf16x8*)&Ws[(nt * 16 + cc) * WSTR + c * 32 + q * 8];
                acc[nt] = __builtin_amdgcn_mfma_f32_16x16x32_bf16(wf, xf[c],
                                                                  acc[nt], 0, 0, 0);
            }
        }

        unsigned short* Cb = outs[z];
#pragma unroll
        for (int pr = 0; pr < 4; pr++) {
#pragma unroll
            for (int h = 0; h < 2; h++) {
                const int nt = pr * 2 + h;
                f32x4 c = acc[nt];
                float o[4] = {c[0], c[1], c[2], c[3]};
                *(uint2*)&sc[cc * SSTR + h * 16 + q * 4] = pack4(o);
            }
            uint4 pk = *(const uint4*)&sc[rtok * SSTR + roct];
            *(uint4*)(Cb + (size_t)(t0 + rtok) * 256 + n0 + pr * 32 + roct) = pk;
        }
    }
}

// ---------------------------------------------------------------------------
// Operand-swapped tall GEMM: C[M,256] = X[M,256] @ B with Bt[n][k]=B[k][n].
// EPI 1: z=acc+bias; Zout=z; Cb = X+silu(z)           fwd layer 0
// EPI 5: z=acc+bias; h2=X+silu(z); dh=alr'* (h2-V);   fwd layer 1 + bwd elem
//        dz=dh*dsilu(z); Cb=dz; Rout=dh; colsum(dz)->gB
// EPI 2: dz0=(acc+Rin)*dsilu(Zin); Cb=dz0; colsum->gB bwd layer 0
// EPI 3: Cb = X + silu(acc+bias)                      retrieved L0
// EPI 4: Cf = X + silu(acc+bias)  (fp32 out)          retrieved L1
// ---------------------------------------------------------------------------
template <int EPI>
__global__ __launch_bounds__(512, 4) void wgemm_k(
    const unsigned short* __restrict__ A, const unsigned short* __restrict__ Bt,
    const float* __restrict__ bias, const unsigned short* __restrict__ Rin,
    const unsigned short* __restrict__ Zin, const unsigned short* __restrict__ Vb,
    const float* __restrict__ alr, float* __restrict__ gB,
    unsigned short* __restrict__ Cb, float* __restrict__ Cf,
    unsigned short* __restrict__ Zout, unsigned short* __restrict__ Rout) {
    __shared__ unsigned short Ws[128 * WSTR];
    __shared__ unsigned short Sc[8][16 * SSTR];
    __shared__ float accsh[128];
    const int n0 = blockIdx.x * 128, m0 = blockIdx.y * 128;
    const int tid = threadIdx.x, lane = tid & 63, wv = tid >> 6;
    const int cc = lane & 15, q = lane >> 4;

    // ---- X-frag loads: 8 instrs off one base (imm offsets)
    const int t0 = m0 + wv * 16;
    const unsigned short* xp = A + (size_t)(t0 + cc) * 256 + q * 8;
    bf16x8 xf[8];
#pragma unroll
    for (int c = 0; c < 8; c++) xf[c] = *(const bf16x8*)(xp + c * 32);

    if (EPI == 2 || EPI == 5) {
        if (tid < 128) accsh[tid] = 0.f;
    }

    // ---- W half-tile fill: [128 n-rows][256 k] shorts, padded stride
#pragma unroll
    for (int it = 0; it < 8; it++) {
        int i = it * 512 + tid;
        int row = i >> 5, g8 = i & 31;
        *(uint4*)&Ws[row * WSTR + g8 * 8] =
            *(const uint4*)(Bt + (size_t)(n0 + row) * 256 + g8 * 8);
    }
    __syncthreads();

    f32x4 acc[8];
#pragma unroll
    for (int t = 0; t < 8; t++) acc[t] = (f32x4){0.f, 0.f, 0.f, 0.f};

#pragma unroll
    for (int c = 0; c < 8; c++) {
#pragma unroll
        for (int nt = 0; nt < 8; nt++) {
            bf16x8 wf = *(const bf16x8*)&Ws[(nt * 16 + cc) * WSTR + c * 32 + q * 8];
            acc[nt] = __builtin_amdgcn_mfma_f32_16x16x32_bf16(wf, xf[c],
                                                              acc[nt], 0, 0, 0);
        }
    }

    // ---- epilogue: lane holds token t0+cc, cols nt*16 + 4q + r (r=0..3)
    const int tok = t0 + cc;
    float lalr = 0.f;
    if (EPI == 5) lalr = alr[tok] * (2.f / 256.f);
    unsigned short* sc = &Sc[wv][0];
    const int rtok = lane >> 2, roct = (lane & 3) * 8;  // repack read indices

#pragma unroll
    for (int pr = 0; pr < 4; pr++) {  // tile pairs (2pr, 2pr+1) = 32 cols
        float o2[2][4], z2[2][4];     // primary / secondary quad outputs
#pragma unroll
        for (int h = 0; h < 2; h++) {
            const int nt = pr * 2 + h;
            const int gcol = n0 + nt * 16 + q * 4;
            const size_t off = (size_t)tok * 256 + gcol;
            f32x4 c = acc[nt];
            float v[4] = {c[0], c[1], c[2], c[3]};
            if (EPI == 1) {
                float bv[4], a[4];
                *(float4*)bv = *(const float4*)(bias + gcol);
                unpack4(*(const uint2*)(A + off), a);
#pragma unroll
                for (int r = 0; r < 4; r++) {
                    float z = v[r] + bv[r];
                    z2[h][r] = z;
                    o2[h][r] = a[r] + siluf(z);
                }
            } else if (EPI == 5) {
                float bv[4], a[4], vv[4];
                *(float4*)bv = *(const float4*)(bias + gcol);
                unpack4(*(const uint2*)(A + off), a);
                unpack4(*(const uint2*)(Vb + off), vv);
#pragma unroll
                for (int r = 0; r < 4; r++) {
                    float z = v[r] + bv[r];
                    float h2 = a[r] + siluf(z);
                    float dh = lalr * (h2 - vv[r]);
                    o2[h][r] = dh * dsiluf(z);  // dz
                    z2[h][r] = dh;              // dh
                }
            } else if (EPI == 2) {
                float ri[4], zi[4];
                unpack4(*(const uint2*)(Rin + off), ri);
                unpack4(*(const uint2*)(Zin + off), zi);
#pragma unroll
                for (int r = 0; r < 4; r++)
                    o2[h][r] = (v[r] + ri[r]) * dsiluf(zi[r]);
            } else {  // EPI 3 / 4
                float bv[4], a[4];
                *(float4*)bv = *(const float4*)(bias + gcol);
                unpack4(*(const uint2*)(A + off), a);
#pragma unroll
                for (int r = 0; r < 4; r++) o2[h][r] = a[r] + siluf(v[r] + bv[r]);
            }
            if (EPI == 4) {  // fp32 direct store: 4 lanes x 16 B = 64 B segs
                *(float4*)(Cf + off) = *(float4*)o2[h];
            }
            if (EPI == 2 || EPI == 5) {  // fused bias-grad column sums of dz
                float s0 = o2[h][0], s1 = o2[h][1], s2 = o2[h][2], s3 = o2[h][3];
#pragma unroll
                for (int m = 1; m < 16; m <<= 1) {
                    s0 += __shfl_xor(s0, m);
                    s1 += __shfl_xor(s1, m);
                    s2 += __shfl_xor(s2, m);
                    s3 += __shfl_xor(s3, m);
                }
                if (cc == 0) {
                    const int lc = nt * 16 + q * 4;
                    atomicAdd(&accsh[lc], s0);
                    atomicAdd(&accsh[lc + 1], s1);
                    atomicAdd(&accsh[lc + 2], s2);
                    atomicAdd(&accsh[lc + 3], s3);
                }
            }
        }
        if (EPI == 4) continue;
        // repack via wave-private scratch -> 64 B segment stores
#pragma unroll
        for (int h = 0; h < 2; h++)
            *(uint2*)&sc[cc * SSTR + h * 16 + q * 4] = pack4(o2[h]);
        uint4 pk = *(const uint4*)&sc[rtok * SSTR + roct];
        *(uint4*)(Cb + (size_t)(t0 + rtok) * 256 + n0 + pr * 32 + roct) = pk;
        if (EPI == 1 || EPI == 5) {  // second output (Zout / Rout)
#pragma unroll
            for (int h = 0; h < 2; h++)
                *(uint2*)&sc[cc * SSTR + h * 16 + q * 4] = pack4(z2[h]);
            uint4 pk2 = *(const uint4*)&sc[rtok * SSTR + roct];
            unsigned short* P2 = (EPI == 1) ? Zout : Rout;
            *(uint4*)(P2 + (size_t)(t0 + rtok) * 256 + n0 + pr * 32 + roct) = pk2;
        }
    }
    if (EPI == 2 || EPI == 5) {  // flush block-local col sums
        __syncthreads();
        if (tid < 128) atomicAdd(&gB[n0 + tid], accsh[tid]);
    }
}

// ---------------------------------------------------------------------------
// Reduction GEMM (weight grads): C[i][j] = sum_t A[t][i] B[t][j], split-K 32.
// Conflict-free swizzled transpose staging + prefetch + 8 waves/block (R9).
// ---------------------------------------------------------------------------
__global__ __launch_bounds__(512, 4) void rgemm_k(
    const unsigned short* __restrict__ Kb, const unsigned short* __restrict__ h1b,
    const unsigned short* __restrict__ dz0b,
    const unsigned short* __restrict__ dz1b, float* __restrict__ pbuf) {
    __shared__ unsigned short As[128 * 64];
    __shared__ unsigned short Bs2[128 * 64];
    const int z = blockIdx.z, layer = z >> 5, zc = z & 31;
    const unsigned short* Ag = layer ? h1b : Kb;
    const unsigned short* Bg = layer ? dz1b : dz0b;
    const int t0 = zc * 1024;
    const int j0 = blockIdx.x * 128, i0 = blockIdx.y * 128;
    const int tid = threadIdx.x, lane = tid & 63, wave = tid >> 6;

    // staging role: threads 0-255 stage A, 256-511 stage B
    const int half = tid >> 8;
    const int t9 = tid & 255;
    const int ptq = t9 >> 4;          // token pair 0..15
    const int pi = (t9 & 15) * 8;     // col group base
    const unsigned short* sg = half ? Bg : Ag;
    const int nb = half ? j0 : i0;
    unsigned int* dst = (unsigned int*)(half ? Bs2 : As);
    const unsigned short* gp = sg + (size_t)(t0 + ptq * 2) * 256 + nb + pi;

    // wave output tile: 64 rows (i) x 32 cols (j)
    const int wr = (wave >> 2) * 64, wc = (wave & 3) * 32;
    const int fr = lane & 15, fkb = lane >> 4;

    f32x4 acc[4][2];
#pragma unroll
    for (int i = 0; i < 4; i++)
#pragma unroll
        for (int j = 0; j < 2; j++) acc[i][j] = (f32x4){0.f, 0.f, 0.f, 0.f};

    uint4 u0 = *(const uint4*)gp;
    uint4 u1 = *(const uint4*)(gp + 256);
    gp += 32 * 256;

    for (int it = 0; it < 32; it++) {
        // transpose-write: pack (token 2q, 2q+1) per col, swizzled slot
        const unsigned int* w0 = (const unsigned int*)&u0;
        const unsigned int* w1 = (const unsigned int*)&u1;
#pragma unroll
        for (int ii = 0; ii < 8; ii++) {
            unsigned int lo = (w0[ii >> 1] >> (16 * (ii & 1))) & 0xFFFFu;
            unsigned int hi = (w1[ii >> 1] >> (16 * (ii & 1))) & 0xFFFFu;
            const int col = pi + ii;
            const int s2 = ((col >> 3) ^ col) & 3;
            const int s4 = ((col >> 2) ^ (col >> 5)) & 1;
            dst[col * 32 + (ptq ^ (s2 << 2) ^ (s4 << 4))] = lo | (hi << 16);
        }
        __syncthreads();
        if (it < 31) {  // prefetch next K-chunk; latency hides under MFMA phase
            u0 = *(const uint4*)gp;
            u1 = *(const uint4*)(gp + 256);
            gp += 32 * 256;
        }
        bf16x8 af[4], bfr[2];
#pragma unroll
        for (int i = 0; i < 4; i++) {
            const int col = wr + i * 16 + fr;
            const int s2 = ((col >> 3) ^ col) & 3;
            const int s4 = ((col >> 2) ^ (col >> 5)) & 1;
            af[i] = *(const bf16x8*)&As[col * 64 + (fkb ^ s2 ^ (s4 << 2)) * 8];
        }
#pragma unroll
        for (int j = 0; j < 2; j++) {
            const int col = wc + j * 16 + fr;
            const int s2 = ((col >> 3) ^ col) & 3;
            const int s4 = ((col >> 2) ^ (col >> 5)) & 1;
            bfr[j] = *(const bf16x8*)&Bs2[col * 64 + (fkb ^ s2 ^ (s4 << 2)) * 8];
        }
#pragma unroll
        for (int i = 0; i < 4; i++)
#pragma unroll
            for (int j = 0; j < 2; j++)
                acc[i][j] = __builtin_amdgcn_mfma_f32_16x16x32_bf16(
                    af[i], bfr[j], acc[i][j], 0, 0, 0);
        __syncthreads();
    }

    float* P = pbuf + (size_t)((layer << 5) + zc) * 65536;
    const int r0 = fkb * 4;
#pragma unroll
    for (int mi = 0; mi < 4; mi++)
#pragma unroll
        for (int ni = 0; ni < 2; ni++) {
            f32x4 c = acc[mi][ni];
#pragma unroll
            for (int r = 0; r < 4; r++)
                P[(size_t)(i0 + wr + mi * 16 + r0 + r) * 256 +
                  (j0 + wc + ni * 16 + fr)] = c[r];
        }
}

// ---------------------------------------------------------------------------
// gradstep: reduce pbuf (32 chunks) -> g; surprises; AdamW for W and b.
// blocks 0..511: weights (256 threads each). block 512: biases.
// ---------------------------------------------------------------------------
__global__ __launch_bounds__(256) void gradstep_k(
    const float* __restrict__ pbuf, const float* __restrict__ Ws,
    const float* __restrict__ bs, const float* __restrict__ accB,
    unsigned short* __restrict__ nWt, float* __restrict__ nb,
    float* __restrict__ outSW, float* __restrict__ outSb) {
    const int bi = blockIdx.x;
    if (bi < 512) {
        const int idx = bi * 256 + threadIdx.x;  // 0..131071
        const int layer = idx >> 16, rc = idx & 65535;
        const float* p = pbuf + (size_t)layer * 32 * 65536 + rc;
        float g = 0.f;
#pragma unroll 8
        for (int c = 0; c < 32; c++) g += p[(size_t)c * 65536];
        outSW[idx] = -g;
        float nw = Ws[idx] * (1.f - LRc * WDc) - LRc * g / (fabsf(g) + EPSc);
        const int l = idx >> 16, k = (idx >> 8) & 255, n = idx & 255;
        nWt[(size_t)l * 65536 + n * 256 + k] = f2b(nw);
    } else {
        for (int i = threadIdx.x; i < 512; i += 256) {
            float g = accB[i];
            outSb[i] = -g;
            nb[i] = bs[i] * (1.f - LRc * WDc) - LRc * g / (fabsf(g) + EPSc);
        }
    }
}

// ---------------------------------------------------------------------------
// prep_all: blocks 0..8191  -> x fp32 -> xb bf16 + alr (one wave per row)
//           blocks 8192..9727 -> weight transpose+cvt (z=0..4) / cvt (z=5)
//           block 9728      -> zero accB[512]
// ---------------------------------------------------------------------------
__global__ __launch_bounds__(256) void prep_all_k(
    const float* __restrict__ x, const float* __restrict__ Wlr,
    const float* __restrict__ blr, const float* __restrict__ Wk,
    const float* __restrict__ Wq, const float* __restrict__ Wv,
    const float* __restrict__ Ws, unsigned short* __restrict__ xb,
    float* __restrict__ alr, unsigned short* __restrict__ wt,
    float* __restrict__ accB) {
    const int bi = blockIdx.x;
    if (bi < 8192) {
        const int wave = threadIdx.x >> 6, lane = threadIdx.x & 63;
        const int r = bi * 4 + wave;
        float4 w = *(const float4*)(Wlr + lane * 4);
        float4 v = *(const float4*)(x + (size_t)r * 256 + lane * 4);
        float s = v.x * w.x + v.y * w.y + v.z * w.z + v.w * w.w;
        unsigned int p0 = (unsigned int)f2b(v.x) | ((unsigned int)f2b(v.y) << 16);
        unsigned int p1 = (unsigned int)f2b(v.z) | ((unsigned int)f2b(v.w) << 16);
        *(uint2*)(xb + (size_t)r * 256 + lane * 4) = make_uint2(p0, p1);
#pragma unroll
        for (int off = 32; off; off >>= 1) s += __shfl_down(s, off);
        if (lane == 0) alr[r] = 0.1f * sigm(s + blr[0]);
    } else if (bi < 9728) {
        const int b = bi - 8192;
        const int z = b >> 8;
        const int idx = (b & 255) * 256 + threadIdx.x;  // 0..65535
        const float* src = z == 0 ? Wk : z == 1 ? Wq : z == 2 ? Wv
                         : z == 3 ? Ws : Ws + 65536;
        unsigned short* dst = wt + (size_t)z * 65536;
        float v = src[idx];
        if (z == 5)
            dst[idx] = f2b(v);
        else
            dst[(idx & 255) * 256 + (idx >> 8)] = f2b(v);
    } else {
        accB[threadIdx.x] = 0.f;
        accB[threadIdx.x + 256] = 0.f;
    }
}

extern "C" void kernel_launch(void* const* d_in, const int* in_sizes, int n_in,
                              void* d_out, int out_size, void* d_ws,
                              size_t ws_size, hipStream_t stream) {
    const float* x = (const float*)d_in[0];
    const float* Wk = (const float*)d_in[1];
    const float* Wq = (const float*)d_in[2];
    const float* Wv = (const float*)d_in[3];
    const float* Wlr = (const float*)d_in[4];
    const float* blr = (const float*)d_in[5];
    const float* Ws = (const float*)d_in[6];
    const float* bs = (const float*)d_in[7];

    unsigned short* S = (unsigned short*)d_ws;
    unsigned short* xb = S + 0 * NM;  // dead after proj; reused as r1b
    unsigned short* Kb = S + 1 * NM;
    unsigned short* Qb = S + 2 * NM;
    unsigned short* Vb = S + 3 * NM;
    unsigned short* z0b = S + 4 * NM;
    unsigned short* h1b = S + 5 * NM;
    unsigned short* dz1b = S + 6 * NM;
    unsigned short* dh2b = S + 7 * NM;
    unsigned short* dz0b = S + 8 * NM;
    float* pbuf = (float*)(S + 9 * NM);  // 16 MB (slot 9): 2 layers x 32 chunks
    unsigned short* r1b = xb;

    unsigned short* wt = S + 11 * NM;
    unsigned short* W0t = wt + 3 * 65536;
    unsigned short* W1t = wt + 4 * 65536;
    unsigned short* W1b = wt + 5 * 65536;
    unsigned short* nW0t = wt + 6 * 65536;
    unsigned short* nW1t = wt + 7 * 65536;
    float* ft = (float*)(wt + 8 * 65536);
    float* alr = ft;              // 32768
    float* accB = ft + 32768;     // 512
    float* nb = accB + 512;       // 512

    float* out_ret = (float*)d_out;
    float* out_sW = out_ret + NM;
    float* out_sb = out_sW + 131072;

    dim3 blk5(512);
    dim3 blk(256);
    dim3 g_tall(2, 256);

    // prep: x->bf16 + alr, weight transpose/cvt, zero accB (one dispatch)
    prep_all_k<<<9729, blk, 0, stream>>>(x, Wlr, blr, Wk, Wq, Wv, Ws, xb, alr,
                                         wt, accB);

    // projections K,Q,V: one dispatch, z-loop inside block
    wgemm3_k<<<g_tall, blk5, 0, stream>>>(xb, wt, Kb, Qb, Vb);

    // fwd layer 0: h1 = K + silu(K@W0 + b0); saves z0
    wgemm_k<1><<<g_tall, blk5, 0, stream>>>(Kb, W0t, bs, nullptr, nullptr,
                                            nullptr, nullptr, nullptr, h1b,
                                            nullptr, z0b, nullptr);

    // fwd layer 1 + bwd elementwise: dz1, dh2 (+ colsum dz1 -> accB[256..])
    wgemm_k<5><<<g_tall, blk5, 0, stream>>>(h1b, W1t, bs + 256, nullptr,
                                            nullptr, Vb, alr, accB + 256,
                                            dz1b, nullptr, nullptr, dh2b);

    // bwd layer 0: dz0 = (dz1@W1^T + dh2) * dsilu(z0) (+ colsum -> accB[0..])
    wgemm_k<2><<<g_tall, blk5, 0, stream>>>(dz1b, W1b, nullptr, dh2b, z0b,
                                            nullptr, nullptr, accB, dz0b,
                                            nullptr, nullptr, nullptr);

    // weight grads: swizzled transpose-on-load split-K partials
    rgemm_k<<<dim3(2, 2, 64), blk5, 0, stream>>>(Kb, h1b, dz0b, dz1b, pbuf);

    // reduce + surprises + AdamW (W and b) in one dispatch
    gradstep_k<<<513, blk, 0, stream>>>(pbuf, Ws, bs, accB, nW0t, nb, out_sW,
                                        out_sb);

    // retrieved with new weights (two tall passes)
    wgemm_k<3><<<g_tall, blk5, 0, stream>>>(Qb, nW0t, nb, nullptr, nullptr,
                                            nullptr, nullptr, nullptr, r1b,
                                            nullptr, nullptr, nullptr);
    wgemm_k<4><<<g_tall, blk5, 0, stream>>>(r1b, nW1t, nb + 256, nullptr,
                                            nullptr, nullptr, nullptr, nullptr,
                                            nullptr, out_ret, nullptr, nullptr);
}